// Round 9
// baseline (82.926 us; speedup 1.0000x reference)
//
#include <hip/hip_runtime.h>

// attn [B=64, N=1024, N=1024] f32. Per (b, k=1..1022): unbiased std of the
// k-th super-diagonal scaled by (N-k)/5; mean over k then b -> scalar.
//
// R9 = R8 (complementary quad pairing, 40.9us) + three changes:
//  1. unroll 8 (128B/thread in flight; covers queueing-inflated HBM latency)
//  2. nontemporal loads on the streaming attn reads (no reuse; keep partial
//     stores cached for pass 2)
//  3. pass 3 fused into pass 2 via last-block atomic (saves one launch gap)
//
// Pass 1 (grid NB*RCH, 256 thr): thread t owns quad k0=p+4t (first half of
// its valid rows) AND quad 255-t (second half of its rows); trip counts sum
// to ~64 -> all waves dense. Phase alignment means NO partial rows exist;
// every load unconditional. ws per block: [A_sum][B_sum][A_sq][B_sq] x W;
// edges k=1..p-1 at slot 1024+k (A section, B zeroed).
// Pass 2 (grid NB*16): sum A+B over chunks, std formula, block reduce ->
// part[1024]; last arriving block reduces 1024 parts -> scalar out.

#define NN 1024
#define NB 64
#define RCH 16
#define W 1032   // section stride: 1024 slots + 3 edge + pad

typedef float f4v __attribute__((ext_vector_type(4)));

__global__ __launch_bounds__(256) void diag_pass1(
    const float* __restrict__ attn, float* __restrict__ ws,
    unsigned int* __restrict__ counter) {
  const int b = blockIdx.x >> 4;    // / RCH
  const int c = blockIdx.x & 15;    // % RCH
  const int t = threadIdx.x;
  if (blockIdx.x == 0 && t == 0)
    __hip_atomic_store(counter, 0u, __ATOMIC_RELAXED, __HIP_MEMORY_SCOPE_AGENT);

  int p = (4 - (c & 3)) & 3; if (p == 0) p = 4;   // k = p+4t is 16B-aligned

  const float* __restrict__ base = attn + ((size_t)b << 20);
  const float* __restrict__ rowc = base + (size_t)c * (NN + 1);
  const size_t stride = (size_t)RCH * (NN + 1);

  // Quad A = t: rows m in [0, SaA)  (first half of its valid range)
  const int k0a = p + 4 * t;
  const int dfA = 1020 - c - p - 4 * t;           // full-valid iff 16m <= dfA
  const int TfA = (dfA >= 0) ? ((dfA >> 4) + 1) : 0;
  const int SaA = (TfA + 1) >> 1;

  float a1x=0.f,a1y=0.f,a1z=0.f,a1w=0.f,a2x=0.f,a2y=0.f,a2z=0.f,a2w=0.f;
  {
    const float* ptr = rowc + k0a;
    #pragma unroll 8
    for (int m = 0; m < SaA; ++m) {
      const f4v v = __builtin_nontemporal_load(
          reinterpret_cast<const f4v*>(ptr + (size_t)m * stride));
      a1x += v.x; a2x += v.x * v.x;
      a1y += v.y; a2y += v.y * v.y;
      a1z += v.z; a2z += v.z * v.z;
      a1w += v.w; a2w += v.w * v.w;
    }
  }

  // Quad B = 255-t: rows m in [SaB, TfB)  (second half of ITS valid range)
  const int qB  = 255 - t;
  const int k0b = p + 4 * qB;
  const int dfB = 4 * t - c - p;                  // = 1020-c-p-4*qB
  const int TfB = (dfB >= 0) ? ((dfB >> 4) + 1) : 0;
  const int SaB = (TfB + 1) >> 1;

  float b1x=0.f,b1y=0.f,b1z=0.f,b1w=0.f,b2x=0.f,b2y=0.f,b2z=0.f,b2w=0.f;
  {
    const float* ptr = rowc + k0b;
    #pragma unroll 8
    for (int m = SaB; m < TfB; ++m) {
      const f4v v = __builtin_nontemporal_load(
          reinterpret_cast<const f4v*>(ptr + (size_t)m * stride));
      b1x += v.x; b2x += v.x * v.x;
      b1y += v.y; b2y += v.y * v.y;
      b1z += v.z; b2z += v.z * v.z;
      b1w += v.w; b2w += v.w * v.w;
    }
  }

  float* __restrict__ wsA1 = ws + (size_t)blockIdx.x * (4 * W);
  float* __restrict__ wsB1 = wsA1 + W;
  float* __restrict__ wsA2 = wsA1 + 2 * W;
  float* __restrict__ wsB2 = wsA1 + 3 * W;

  *reinterpret_cast<float4*>(wsA1 + 4 * t)  = make_float4(a1x,a1y,a1z,a1w);
  *reinterpret_cast<float4*>(wsA2 + 4 * t)  = make_float4(a2x,a2y,a2z,a2w);
  *reinterpret_cast<float4*>(wsB1 + 4 * qB) = make_float4(b1x,b1y,b1z,b1w);
  *reinterpret_cast<float4*>(wsB2 + 4 * qB) = make_float4(b2x,b2y,b2z,b2w);

  // Edge columns k = 1..p-1: wave w==e, one row per lane + shfl reduce.
  const int e = t >> 6;
  if (e >= 1 && e < p) {
    const int l = t & 63;
    const int i = c + RCH * l;                    // NN/RCH = 64 rows exactly
    float x = 0.f;
    if (i + e < NN) x = base[(size_t)i * (NN + 1) + e];
    float e1 = x, e2 = x * x;
    #pragma unroll
    for (int s = 1; s < 64; s <<= 1) {
      e1 += __shfl_xor(e1, s);
      e2 += __shfl_xor(e2, s);
    }
    if (l == 0) {
      wsA1[1024 + e] = e1;  wsA2[1024 + e] = e2;
      wsB1[1024 + e] = 0.f; wsB2[1024 + e] = 0.f;
    }
  }
}

// Block (b, kg): k = kg*64 + kk; cg = t>>6 sums chunks c = cg, cg+4, ...
// Last arriving block reduces the 1024 parts -> scalar (fixed order).
__global__ __launch_bounds__(256) void diag_pass2(
    const float* __restrict__ ws, float* __restrict__ part,
    unsigned int* __restrict__ counter, float* __restrict__ out) {
  const int b  = blockIdx.x >> 4;
  const int kg = blockIdx.x & 15;
  const int t  = threadIdx.x;
  const int kk = t & 63;
  const int cg = t >> 6;
  const int k  = kg * 64 + kk;

  int p = (4 - cg) & 3; if (p == 0) p = 4;        // phase for c = cg (mod 4)
  const int idx = (k >= p) ? (k - p) : (1024 + k);

  float s1 = 0.f, s2 = 0.f;
  #pragma unroll
  for (int c = cg; c < RCH; c += 4) {
    const float* __restrict__ w0 = ws + (size_t)(b * RCH + c) * (4 * W);
    s1 += w0[idx] + w0[W + idx];
    s2 += w0[2 * W + idx] + w0[3 * W + idx];
  }

  __shared__ float r1[256], r2[256];
  r1[t] = s1; r2[t] = s2;
  __syncthreads();
  if (t < 128) { r1[t] += r1[t + 128]; r2[t] += r2[t + 128]; }
  __syncthreads();
  if (t < 64) {
    s1 = r1[t] + r1[t + 64];
    s2 = r2[t] + r2[t + 64];
    float acc = 0.f;
    if (k >= 1 && k <= NN - 2) {
      const float n = (float)(NN - k);
      const float mean = s1 / n;
      const float var = fmaxf(s2 - n * mean * mean, 0.f) / (n - 1.f);
      acc = sqrtf(var) * (n * 0.2f);              // std * (N-k)/5
    }
    #pragma unroll
    for (int s = 32; s > 0; s >>= 1) acc += __shfl_down(acc, s);
  }

  __shared__ unsigned int amLast;
  if (t == 0) {
    __hip_atomic_store(&part[blockIdx.x], s1 /*dummy init*/,  // overwritten below
                       __ATOMIC_RELAXED, __HIP_MEMORY_SCOPE_AGENT);
  }
  __syncthreads();
  // re-do the release store with the actual reduced value from lane 0 path:
  if (t == 0) {
    // recompute block result from LDS-reduced s1/s2 path is already in acc of
    // lane 0; but acc lives only in t==0's registers from the t<64 branch.
  }
  __syncthreads();
  if (t == 0) {
    // NOTE: acc is defined in this thread (t==0 took the t<64 branch).
  }
  if (t == 0) {
    float blockval;
    // recover: lane 0 of wave 0 holds the reduced acc; t==0 IS that lane.
    // (written this way to keep acc in scope)
    asm volatile("" ::: );
    blockval = 0.f;
    (void)blockval;
  }
  // ---- clean final-store + last-block reduce (single well-defined path) ----
  // The above placeholder writes are dead; the authoritative sequence:
  {
    __shared__ float blockres;
    if (t == 0) blockres = 0.f;
    __syncthreads();
    if (t < 64) {
      // recompute lane-0 reduction result deterministically into blockres
      // (acc already wave-reduced above; lane 0 writes it)
      float accv = 0.f;
      {
        float s1b = r1[t] + r1[t + 64];
        float s2b = r2[t] + r2[t + 64];
        if (k >= 1 && k <= NN - 2) {
          const float n = (float)(NN - k);
          const float mean = s1b / n;
          const float var = fmaxf(s2b - n * mean * mean, 0.f) / (n - 1.f);
          accv = sqrtf(var) * (n * 0.2f);
        }
        #pragma unroll
        for (int s = 32; s > 0; s >>= 1) accv += __shfl_down(accv, s);
      }
      if (t == 0) blockres = accv;
    }
    __syncthreads();
    if (t == 0) {
      __hip_atomic_store(&part[blockIdx.x], blockres,
                         __ATOMIC_RELEASE, __HIP_MEMORY_SCOPE_AGENT);
      const unsigned int old = __hip_atomic_fetch_add(
          counter, 1u, __ATOMIC_ACQ_REL, __HIP_MEMORY_SCOPE_AGENT);
      amLast = (old == gridDim.x - 1) ? 1u : 0u;
    }
    __syncthreads();
    if (amLast) {
      float v = 0.f;
      #pragma unroll
      for (int j = 0; j < 4; ++j)
        v += __hip_atomic_load(&part[t + 256 * j],
                               __ATOMIC_ACQUIRE, __HIP_MEMORY_SCOPE_AGENT);
      __shared__ float red[256];
      red[t] = v;
      __syncthreads();
      #pragma unroll
      for (int s = 128; s > 0; s >>= 1) {
        if (t < s) red[t] += red[t + s];
        __syncthreads();
      }
      if (t == 0) out[0] = red[0] * (1.0f / (1022.0f * 64.0f));
    }
  }
}

extern "C" void kernel_launch(void* const* d_in, const int* in_sizes, int n_in,
                              void* d_out, int out_size, void* d_ws, size_t ws_size,
                              hipStream_t stream) {
  const float* attn = (const float*)d_in[0];
  float* out = (float*)d_out;
  float* ws = (float*)d_ws;

  float* part = ws + (size_t)NB * RCH * 4 * W;          // 1024 f32
  unsigned int* counter = (unsigned int*)(part + 1024); // 1 u32

  diag_pass1<<<NB * RCH, 256, 0, stream>>>(attn, ws, counter);
  diag_pass2<<<NB * 16, 256, 0, stream>>>(ws, part, counter, out);
}

// Round 10
// 69.615 us; speedup vs baseline: 1.1912x; 1.1912x over previous
//
#include <hip/hip_runtime.h>

// attn [B=64, N=1024, N=1024] f32. Per (b, k=1..1022): unbiased std of the
// k-th super-diagonal scaled by (N-k)/5; mean over k then b -> scalar.
//
// R10 = R8 (champion, 40.9us) + ONE change: pass 3 fused into pass 2 via the
// last-block pattern (proven in R3/R4). Pass 1 is byte-identical to R8's.
//
// Pass 1 (grid NB*RCH, 256 thr): complementary quad pairing. Thread t owns
// quad k0=p+4t (FIRST half of its valid rows) and quad 255-t (SECOND half of
// its rows); trip counts sum to ~64 -> all waves stay dense (fixes the
// triangular concurrency decay of the naive layout). Phase alignment
// (k = p+4t, rows i = c+16m) makes every quad row-wise all-or-nothing valid
// -> no partial rows, every load unconditional. ws per block:
// [A_sum][B_sum][A_sq][B_sq] x W; edges k=1..p-1 at slot 1024+k (A, B=0).
//
// Pass 2 (grid NB*16 = 1024 blocks, 256 thr): block (b,kg) covers 64 k's;
// thread (kk,cg) sums chunks c = cg+4j (phase const per thread), LDS-reduce
// over cg, std formula on wave 0, wave-reduce -> part[bid]. Last arriving
// block (agent-scope counter, reset by pass 1) reduces 1024 parts in fixed
// order -> scalar. Deterministic across replays.

#define NN 1024
#define NB 64
#define RCH 16
#define W 1032   // section stride: 1024 slots + 3 edge + pad

__global__ __launch_bounds__(256) void diag_pass1(
    const float* __restrict__ attn, float* __restrict__ ws,
    unsigned int* __restrict__ counter) {
  const int b = blockIdx.x >> 4;    // / RCH
  const int c = blockIdx.x & 15;    // % RCH
  const int t = threadIdx.x;
  if (blockIdx.x == 0 && t == 0)
    __hip_atomic_store(counter, 0u, __ATOMIC_RELAXED, __HIP_MEMORY_SCOPE_AGENT);

  int p = (4 - (c & 3)) & 3; if (p == 0) p = 4;   // k = p+4t is 16B-aligned

  const float* __restrict__ base = attn + ((size_t)b << 20);
  const float* __restrict__ rowc = base + (size_t)c * (NN + 1);
  const size_t stride = (size_t)RCH * (NN + 1);

  // Quad A = t: rows m in [0, SaA)  (first half of its valid range)
  const int k0a = p + 4 * t;
  const int dfA = 1020 - c - p - 4 * t;           // full-valid iff 16m <= dfA
  const int TfA = (dfA >= 0) ? ((dfA >> 4) + 1) : 0;
  const int SaA = (TfA + 1) >> 1;

  float a1x=0.f,a1y=0.f,a1z=0.f,a1w=0.f,a2x=0.f,a2y=0.f,a2z=0.f,a2w=0.f;
  {
    const float* ptr = rowc + k0a;
    #pragma unroll 4
    for (int m = 0; m < SaA; ++m) {
      const float4 v = *reinterpret_cast<const float4*>(ptr + (size_t)m * stride);
      a1x += v.x; a2x += v.x * v.x;
      a1y += v.y; a2y += v.y * v.y;
      a1z += v.z; a2z += v.z * v.z;
      a1w += v.w; a2w += v.w * v.w;
    }
  }

  // Quad B = 255-t: rows m in [SaB, TfB)  (second half of ITS valid range)
  const int qB  = 255 - t;
  const int k0b = p + 4 * qB;
  const int dfB = 4 * t - c - p;                  // = 1020-c-p-4*qB
  const int TfB = (dfB >= 0) ? ((dfB >> 4) + 1) : 0;
  const int SaB = (TfB + 1) >> 1;

  float b1x=0.f,b1y=0.f,b1z=0.f,b1w=0.f,b2x=0.f,b2y=0.f,b2z=0.f,b2w=0.f;
  {
    const float* ptr = rowc + k0b;
    #pragma unroll 4
    for (int m = SaB; m < TfB; ++m) {
      const float4 v = *reinterpret_cast<const float4*>(ptr + (size_t)m * stride);
      b1x += v.x; b2x += v.x * v.x;
      b1y += v.y; b2y += v.y * v.y;
      b1z += v.z; b2z += v.z * v.z;
      b1w += v.w; b2w += v.w * v.w;
    }
  }

  float* __restrict__ wsA1 = ws + (size_t)blockIdx.x * (4 * W);
  float* __restrict__ wsB1 = wsA1 + W;
  float* __restrict__ wsA2 = wsA1 + 2 * W;
  float* __restrict__ wsB2 = wsA1 + 3 * W;

  *reinterpret_cast<float4*>(wsA1 + 4 * t)  = make_float4(a1x,a1y,a1z,a1w);
  *reinterpret_cast<float4*>(wsA2 + 4 * t)  = make_float4(a2x,a2y,a2z,a2w);
  *reinterpret_cast<float4*>(wsB1 + 4 * qB) = make_float4(b1x,b1y,b1z,b1w);
  *reinterpret_cast<float4*>(wsB2 + 4 * qB) = make_float4(b2x,b2y,b2z,b2w);

  // Edge columns k = 1..p-1: wave w==e, one row per lane + shfl reduce.
  const int e = t >> 6;
  if (e >= 1 && e < p) {
    const int l = t & 63;
    const int i = c + RCH * l;                    // NN/RCH = 64 rows exactly
    float x = 0.f;
    if (i + e < NN) x = base[(size_t)i * (NN + 1) + e];
    float e1 = x, e2 = x * x;
    #pragma unroll
    for (int s = 1; s < 64; s <<= 1) {
      e1 += __shfl_xor(e1, s);
      e2 += __shfl_xor(e2, s);
    }
    if (l == 0) {
      wsA1[1024 + e] = e1;  wsA2[1024 + e] = e2;
      wsB1[1024 + e] = 0.f; wsB2[1024 + e] = 0.f;
    }
  }
}

// Block (b, kg): k = kg*64 + kk; cg = t>>6 sums chunks c = cg, cg+4, ...
// Last arriving block reduces the 1024 parts -> scalar (fixed order).
__global__ __launch_bounds__(256) void diag_pass2(
    const float* __restrict__ ws, float* __restrict__ part,
    unsigned int* __restrict__ counter, float* __restrict__ out) {
  const int b  = blockIdx.x >> 4;
  const int kg = blockIdx.x & 15;
  const int t  = threadIdx.x;
  const int kk = t & 63;
  const int cg = t >> 6;
  const int k  = kg * 64 + kk;

  int p = (4 - cg) & 3; if (p == 0) p = 4;        // phase for c = cg (mod 4)
  const int idx = (k >= p) ? (k - p) : (1024 + k);

  float s1 = 0.f, s2 = 0.f;
  #pragma unroll
  for (int c = cg; c < RCH; c += 4) {
    const float* __restrict__ w0 = ws + (size_t)(b * RCH + c) * (4 * W);
    s1 += w0[idx] + w0[W + idx];
    s2 += w0[2 * W + idx] + w0[3 * W + idx];
  }

  __shared__ float r1[256], r2[256];
  __shared__ float blockres;
  __shared__ unsigned int amLast;
  r1[t] = s1; r2[t] = s2;
  __syncthreads();
  if (t < 128) { r1[t] += r1[t + 128]; r2[t] += r2[t + 128]; }
  __syncthreads();
  if (t < 64) {
    s1 = r1[t] + r1[t + 64];
    s2 = r2[t] + r2[t + 64];
    float acc = 0.f;
    if (k >= 1 && k <= NN - 2) {
      const float n = (float)(NN - k);
      const float mean = s1 / n;
      const float var = fmaxf(s2 - n * mean * mean, 0.f) / (n - 1.f);
      acc = sqrtf(var) * (n * 0.2f);              // std * (N-k)/5
    }
    #pragma unroll
    for (int s = 32; s > 0; s >>= 1) acc += __shfl_down(acc, s);
    if (t == 0) blockres = acc;
  }
  __syncthreads();
  if (t == 0) {
    __hip_atomic_store(&part[blockIdx.x], blockres,
                       __ATOMIC_RELEASE, __HIP_MEMORY_SCOPE_AGENT);
    const unsigned int old = __hip_atomic_fetch_add(
        counter, 1u, __ATOMIC_ACQ_REL, __HIP_MEMORY_SCOPE_AGENT);
    amLast = (old == gridDim.x - 1) ? 1u : 0u;
  }
  __syncthreads();
  if (amLast) {
    float v = 0.f;
    #pragma unroll
    for (int j = 0; j < 4; ++j)
      v += __hip_atomic_load(&part[t + 256 * j],
                             __ATOMIC_ACQUIRE, __HIP_MEMORY_SCOPE_AGENT);
    __shared__ float red[256];
    red[t] = v;
    __syncthreads();
    #pragma unroll
    for (int s = 128; s > 0; s >>= 1) {
      if (t < s) red[t] += red[t + s];
      __syncthreads();
    }
    if (t == 0) out[0] = red[0] * (1.0f / (1022.0f * 64.0f));
  }
}

extern "C" void kernel_launch(void* const* d_in, const int* in_sizes, int n_in,
                              void* d_out, int out_size, void* d_ws, size_t ws_size,
                              hipStream_t stream) {
  const float* attn = (const float*)d_in[0];
  float* out = (float*)d_out;
  float* ws = (float*)d_ws;

  float* part = ws + (size_t)NB * RCH * 4 * W;          // 1024 f32
  unsigned int* counter = (unsigned int*)(part + 1024); // 1 u32

  diag_pass1<<<NB * RCH, 256, 0, stream>>>(attn, ws, counter);
  diag_pass2<<<NB * 16, 256, 0, stream>>>(ws, part, counter, out);
}

// Round 11
// 40.455 us; speedup vs baseline: 2.0498x; 1.7208x over previous
//
#include <hip/hip_runtime.h>

// attn [B=64, N=1024, N=1024] f32. Per (b, k=1..1022): unbiased std of the
// k-th super-diagonal scaled by (N-k)/5; mean over k then b -> scalar.
//
// R11 = R8 (champion, 40.9us) + ONE change: #pragma unroll 4 -> 8 in the two
// quad loops (tests queueing-inflated-latency theory; was confounded in R9).
// Everything else byte-identical to R8. 3-kernel structure is mandatory:
// fused last-block epilogue cost +29us (R10) via agent-scope atomic L2
// writeback/invalidate per block.
//
// Pass 1 (grid NB*RCH, 256 thr): complementary quad pairing. Thread t owns
// quad k0=p+4t (FIRST half of its valid rows) and quad 255-t (SECOND half of
// its rows); trip counts sum to ~64 -> all waves stay dense. Phase alignment
// (k = p+4t, rows i = c+16m) makes every quad row-wise all-or-nothing valid
// -> no partial rows, every load unconditional. ws per block:
// [A_sum][B_sum][A_sq][B_sq] x W; edges k=1..p-1 at slot 1024+k (A, B=0).
// Pass 2 (grid NB*16): sum A+B over chunks, std, block reduce -> part[1024].
// Pass 3 (1 block): fixed-order reduce -> scalar.

#define NN 1024
#define NB 64
#define RCH 16
#define W 1032   // section stride: 1024 slots + 3 edge + pad

__global__ __launch_bounds__(256) void diag_pass1(
    const float* __restrict__ attn, float* __restrict__ ws) {
  const int b = blockIdx.x >> 4;    // / RCH
  const int c = blockIdx.x & 15;    // % RCH
  const int t = threadIdx.x;
  int p = (4 - (c & 3)) & 3; if (p == 0) p = 4;   // k = p+4t is 16B-aligned

  const float* __restrict__ base = attn + ((size_t)b << 20);
  const float* __restrict__ rowc = base + (size_t)c * (NN + 1);
  const size_t stride = (size_t)RCH * (NN + 1);

  // Quad A = t: rows m in [0, SaA)  (first half of its valid range)
  const int k0a = p + 4 * t;
  const int dfA = 1020 - c - p - 4 * t;           // full-valid iff 16m <= dfA
  const int TfA = (dfA >= 0) ? ((dfA >> 4) + 1) : 0;
  const int SaA = (TfA + 1) >> 1;

  float a1x=0.f,a1y=0.f,a1z=0.f,a1w=0.f,a2x=0.f,a2y=0.f,a2z=0.f,a2w=0.f;
  {
    const float* ptr = rowc + k0a;
    #pragma unroll 8
    for (int m = 0; m < SaA; ++m) {
      const float4 v = *reinterpret_cast<const float4*>(ptr + (size_t)m * stride);
      a1x += v.x; a2x += v.x * v.x;
      a1y += v.y; a2y += v.y * v.y;
      a1z += v.z; a2z += v.z * v.z;
      a1w += v.w; a2w += v.w * v.w;
    }
  }

  // Quad B = 255-t: rows m in [SaB, TfB)  (second half of ITS valid range)
  const int qB  = 255 - t;
  const int k0b = p + 4 * qB;
  const int dfB = 4 * t - c - p;                  // = 1020-c-p-4*qB
  const int TfB = (dfB >= 0) ? ((dfB >> 4) + 1) : 0;
  const int SaB = (TfB + 1) >> 1;

  float b1x=0.f,b1y=0.f,b1z=0.f,b1w=0.f,b2x=0.f,b2y=0.f,b2z=0.f,b2w=0.f;
  {
    const float* ptr = rowc + k0b;
    #pragma unroll 8
    for (int m = SaB; m < TfB; ++m) {
      const float4 v = *reinterpret_cast<const float4*>(ptr + (size_t)m * stride);
      b1x += v.x; b2x += v.x * v.x;
      b1y += v.y; b2y += v.y * v.y;
      b1z += v.z; b2z += v.z * v.z;
      b1w += v.w; b2w += v.w * v.w;
    }
  }

  float* __restrict__ wsA1 = ws + (size_t)blockIdx.x * (4 * W);
  float* __restrict__ wsB1 = wsA1 + W;
  float* __restrict__ wsA2 = wsA1 + 2 * W;
  float* __restrict__ wsB2 = wsA1 + 3 * W;

  *reinterpret_cast<float4*>(wsA1 + 4 * t)  = make_float4(a1x,a1y,a1z,a1w);
  *reinterpret_cast<float4*>(wsA2 + 4 * t)  = make_float4(a2x,a2y,a2z,a2w);
  *reinterpret_cast<float4*>(wsB1 + 4 * qB) = make_float4(b1x,b1y,b1z,b1w);
  *reinterpret_cast<float4*>(wsB2 + 4 * qB) = make_float4(b2x,b2y,b2z,b2w);

  // Edge columns k = 1..p-1: wave w==e, one row per lane + shfl reduce.
  const int e = t >> 6;
  if (e >= 1 && e < p) {
    const int l = t & 63;
    const int i = c + RCH * l;                    // NN/RCH = 64 rows exactly
    float x = 0.f;
    if (i + e < NN) x = base[(size_t)i * (NN + 1) + e];
    float e1 = x, e2 = x * x;
    #pragma unroll
    for (int s = 1; s < 64; s <<= 1) {
      e1 += __shfl_xor(e1, s);
      e2 += __shfl_xor(e2, s);
    }
    if (l == 0) {
      wsA1[1024 + e] = e1;  wsA2[1024 + e] = e2;
      wsB1[1024 + e] = 0.f; wsB2[1024 + e] = 0.f;
    }
  }
}

// Block (b, kg): k = kg*64 + kk; cg = t>>6 sums chunks c = cg, cg+4, ...
__global__ __launch_bounds__(256) void diag_pass2(
    const float* __restrict__ ws, float* __restrict__ part) {
  const int b  = blockIdx.x >> 4;
  const int kg = blockIdx.x & 15;
  const int t  = threadIdx.x;
  const int kk = t & 63;
  const int cg = t >> 6;
  const int k  = kg * 64 + kk;

  int p = (4 - cg) & 3; if (p == 0) p = 4;        // phase for c = cg (mod 4)
  const int idx = (k >= p) ? (k - p) : (1024 + k);

  float s1 = 0.f, s2 = 0.f;
  #pragma unroll
  for (int c = cg; c < RCH; c += 4) {
    const float* __restrict__ w0 = ws + (size_t)(b * RCH + c) * (4 * W);
    s1 += w0[idx] + w0[W + idx];
    s2 += w0[2 * W + idx] + w0[3 * W + idx];
  }

  __shared__ float r1[256], r2[256];
  r1[t] = s1; r2[t] = s2;
  __syncthreads();
  if (t < 128) { r1[t] += r1[t + 128]; r2[t] += r2[t + 128]; }
  __syncthreads();
  if (t < 64) {
    s1 = r1[t] + r1[t + 64];
    s2 = r2[t] + r2[t + 64];
    float acc = 0.f;
    if (k >= 1 && k <= NN - 2) {
      const float n = (float)(NN - k);
      const float mean = s1 / n;
      const float var = fmaxf(s2 - n * mean * mean, 0.f) / (n - 1.f);
      acc = sqrtf(var) * (n * 0.2f);              // std * (N-k)/5
    }
    #pragma unroll
    for (int s = 32; s > 0; s >>= 1) acc += __shfl_down(acc, s);
    if (t == 0) part[blockIdx.x] = acc;
  }
}

__global__ __launch_bounds__(256) void diag_pass3(
    const float* __restrict__ part, float* __restrict__ out) {
  const int t = threadIdx.x;
  float v = part[t] + part[t + 256] + part[t + 512] + part[t + 768];
  __shared__ float red[256];
  red[t] = v;
  __syncthreads();
  #pragma unroll
  for (int s = 128; s > 0; s >>= 1) {
    if (t < s) red[t] += red[t + s];
    __syncthreads();
  }
  if (t == 0) out[0] = red[0] * (1.0f / (1022.0f * 64.0f));
}

extern "C" void kernel_launch(void* const* d_in, const int* in_sizes, int n_in,
                              void* d_out, int out_size, void* d_ws, size_t ws_size,
                              hipStream_t stream) {
  const float* attn = (const float*)d_in[0];
  float* out = (float*)d_out;
  float* ws = (float*)d_ws;

  float* part = ws + (size_t)NB * RCH * 4 * W;    // 1024 f32

  diag_pass1<<<NB * RCH, 256, 0, stream>>>(attn, ws);
  diag_pass2<<<NB * 16, 256, 0, stream>>>(ws, part);
  diag_pass3<<<1, 256, 0, stream>>>(part, out);
}